// Round 2
// baseline (397.067 us; speedup 1.0000x reference)
//
#include <hip/hip_runtime.h>
#include <hip/hip_bf16.h>

#define HH 1024
#define NHEADS 8
#define HDIM 128
#define BB 4
#define TT 2048
#define MROWS (BB*TT)   // 8192

typedef __bf16 bf16;
typedef __bf16 bf16x4 __attribute__((ext_vector_type(4)));
typedef __bf16 bf16x8 __attribute__((ext_vector_type(8)));
typedef float floatx4 __attribute__((ext_vector_type(4)));

// async global->LDS DMA, 16B per lane; lds dest = wave-uniform base + lane*16
__device__ __forceinline__ void gl2lds16(const void* g, void* l) {
    __builtin_amdgcn_global_load_lds(
        (const __attribute__((address_space(1))) unsigned int*)g,
        (__attribute__((address_space(3))) unsigned int*)l, 16, 0, 0);
}

// ---------------- LayerNorm: one block per row, f32 in -> bf16 out ----------------
__global__ __launch_bounds__(256) void ln_k(const float* __restrict__ x,
                                            const float* __restrict__ g,
                                            const float* __restrict__ be,
                                            bf16* __restrict__ xn) {
    int row = blockIdx.x;
    int t = threadIdx.x;
    float4 v4 = ((const float4*)(x + (size_t)row * HH))[t];
    const float* v = (const float*)&v4;
    float s = v[0] + v[1] + v[2] + v[3];
    float s2 = v[0]*v[0] + v[1]*v[1] + v[2]*v[2] + v[3]*v[3];
#pragma unroll
    for (int off = 32; off > 0; off >>= 1) {
        s  += __shfl_down(s,  off);
        s2 += __shfl_down(s2, off);
    }
    __shared__ float red[8];
    if ((t & 63) == 0) { red[t >> 6] = s; red[(t >> 6) + 4] = s2; }
    __syncthreads();
    s  = red[0] + red[1] + red[2] + red[3];
    s2 = red[4] + red[5] + red[6] + red[7];
    float mu  = s * (1.f / HH);
    float var = s2 * (1.f / HH) - mu * mu;
    float rs  = rsqrtf(var + 1e-5f);
    float4 g4 = ((const float4*)g)[t];
    float4 b4 = ((const float4*)be)[t];
    const float* gv = (const float*)&g4;
    const float* bv = (const float*)&b4;
    bf16x4 o;
#pragma unroll
    for (int z = 0; z < 4; z++) o[z] = (bf16)((v[z] - mu) * rs * gv[z] + bv[z]);
    ((bf16x4*)(xn + (size_t)row * HH))[t] = o;
}

// ---------------- Weight convert f32 -> bf16 (1024x1024) ----------------
__global__ __launch_bounds__(256) void convw_k(const float* __restrict__ W,
                                               bf16* __restrict__ Wb) {
    int idx = blockIdx.x * 256 + threadIdx.x;
    float4 v4 = ((const float4*)W)[idx];
    const float* v = (const float*)&v4;
    bf16x4 o;
#pragma unroll
    for (int z = 0; z < 4; z++) o[z] = (bf16)v[z];
    ((bf16x4*)Wb)[idx] = o;
}

// ===================================================================================
// Fused QK projection: C[8192 x 2048] = A[8192x1024] * Wqk[2048x1024]^T, col<1024 -> Q,
// col>=1024 -> K. 8-phase-style deep pipeline:
//   BM=256, BN=128, BK=64, 512 thr (8 waves, WM=4 x WN=2, wave tile 64x64).
//   3 LDS K-tile buffers (A 32KB + B 16KB each; 144KB total) -> compute buf kt%3,
//   stage buf (kt+2)%3: compute buffer is stable for the whole iteration (no WAR/RAW
//   hazard with this iter's DMA regardless of scheduling).
//   4 phases/K-tile: {ds_read frag subtile || stage 1 half-tile || barrier || 8 MFMA
//   || barrier}; ONE vmcnt checkpoint per K-tile, counted vmcnt(6) (= tile kt+2's 6
//   loads allowed in flight) -- tile kt+1 proven resident at next iter start. Never
//   drains to 0 in the main loop (T3+T4); setprio(1) around MFMA clusters (T5).
//   LDS rows are 128B; chunk ^= (row&7) swizzle (G4-verified) -> conflict-free
//   ds_read_b128; applied via pre-swizzled per-lane DMA source, linear LDS dest.
//   XCD-chunked block swizzle (512 % 8 == 0 -> bijective simple form).
// ===================================================================================
#define KT16 16
__global__ __launch_bounds__(512, 2) void gemm_qk8_k(const bf16* __restrict__ A,
                                                     const bf16* __restrict__ W,
                                                     bf16* __restrict__ Qo,
                                                     bf16* __restrict__ Ko) {
    __shared__ __align__(16) bf16 As[3][256 * 64];   // 96 KB
    __shared__ __align__(16) bf16 Bs[3][128 * 64];   // 48 KB
    const int K = HH;
    int t = threadIdx.x, lane = t & 63, w = t >> 6;
    int wm = w >> 1, wn = w & 1;            // wm 0..3, wn 0..1
    int quad = lane >> 4, cl = lane & 15;

    int bid = blockIdx.x;
    int v = (bid & 7) * 64 + (bid >> 3);    // XCD-chunked, bijective (512%8==0)
    int m0 = (v >> 4) * 256;
    int n0 = (v & 15) * 128;

    int rsub = lane >> 3;                   // 0..7
    int xsw = ((lane & 7) ^ rsub) * 8;      // pre-swizzled source col (elems)
    int psw = cl & 7;                       // frag-read swizzle

    auto stageA = [&](int kt, int sb, int h) {
#pragma unroll
        for (int i = 0; i < 2; i++) {
            int row = h * 128 + w * 16 + i * 8 + rsub;
            gl2lds16(&A[(size_t)(m0 + row) * K + kt * 64 + xsw],
                     (char*)&As[sb][0] + h * 16384 + w * 2048 + i * 1024);
        }
    };
    auto stageB = [&](int kt, int sb) {
#pragma unroll
        for (int i = 0; i < 2; i++) {
            int row = w * 16 + i * 8 + rsub;
            gl2lds16(&W[(size_t)(n0 + row) * K + kt * 64 + xsw],
                     (char*)&Bs[sb][0] + w * 2048 + i * 1024);
        }
    };

    floatx4 acc[4][4] = {};
    bf16x8 a[2][2], b0[2][2], b1[2][2];

    // prologue: stage tiles 0,1 (12 loads/thread); vmcnt(6) -> tile0 resident
    stageA(0, 0, 0); stageA(0, 0, 1); stageB(0, 0);
    stageA(1, 1, 0); stageA(1, 1, 1); stageB(1, 1);
    asm volatile("s_waitcnt vmcnt(6)" ::: "memory");
    __builtin_amdgcn_s_barrier();
    __builtin_amdgcn_sched_barrier(0);

#pragma unroll 1
    for (int kt = 0; kt < KT16; ++kt) {
        int rb = kt % 3;
        int sb = (kt + 2) % 3;
        bool st = (kt + 2) < KT16;
        const bf16* Ar = &As[rb][0];
        const bf16* Br = &Bs[rb][0];

        // ---- P1: read a(m0,m1), b0(n0,n1); stage A-half0; MFMA acc[0,1][0,1]
#pragma unroll
        for (int mp = 0; mp < 2; mp++)
#pragma unroll
            for (int ks = 0; ks < 2; ks++)
                a[mp][ks] = *(const bf16x8*)&Ar[(wm * 64 + mp * 16 + cl) * 64 + (((ks * 4 + quad) ^ psw) * 8)];
#pragma unroll
        for (int np = 0; np < 2; np++)
#pragma unroll
            for (int ks = 0; ks < 2; ks++)
                b0[np][ks] = *(const bf16x8*)&Br[(wn * 64 + np * 16 + cl) * 64 + (((ks * 4 + quad) ^ psw) * 8)];
        if (st) stageA(kt + 2, sb, 0);
        __builtin_amdgcn_s_barrier();
        __builtin_amdgcn_sched_barrier(0);
        __builtin_amdgcn_s_setprio(1);
#pragma unroll
        for (int mp = 0; mp < 2; mp++)
#pragma unroll
            for (int np = 0; np < 2; np++)
#pragma unroll
                for (int ks = 0; ks < 2; ks++)
                    acc[mp][np] = __builtin_amdgcn_mfma_f32_16x16x32_bf16(a[mp][ks], b0[np][ks], acc[mp][np], 0, 0, 0);
        __builtin_amdgcn_s_setprio(0);
        __builtin_amdgcn_s_barrier();
        __builtin_amdgcn_sched_barrier(0);

        // ---- P2: read b1(n2,n3); stage A-half1; MFMA acc[0,1][2,3]
#pragma unroll
        for (int np = 0; np < 2; np++)
#pragma unroll
            for (int ks = 0; ks < 2; ks++)
                b1[np][ks] = *(const bf16x8*)&Br[(wn * 64 + 32 + np * 16 + cl) * 64 + (((ks * 4 + quad) ^ psw) * 8)];
        if (st) stageA(kt + 2, sb, 1);
        __builtin_amdgcn_s_barrier();
        __builtin_amdgcn_sched_barrier(0);
        __builtin_amdgcn_s_setprio(1);
#pragma unroll
        for (int mp = 0; mp < 2; mp++)
#pragma unroll
            for (int np = 0; np < 2; np++)
#pragma unroll
                for (int ks = 0; ks < 2; ks++)
                    acc[mp][np + 2] = __builtin_amdgcn_mfma_f32_16x16x32_bf16(a[mp][ks], b1[np][ks], acc[mp][np + 2], 0, 0, 0);
        __builtin_amdgcn_s_setprio(0);
        __builtin_amdgcn_s_barrier();
        __builtin_amdgcn_sched_barrier(0);

        // ---- P3: read a(m2,m3); stage B; MFMA acc[2,3][2,3]
#pragma unroll
        for (int mp = 0; mp < 2; mp++)
#pragma unroll
            for (int ks = 0; ks < 2; ks++)
                a[mp][ks] = *(const bf16x8*)&Ar[(wm * 64 + 32 + mp * 16 + cl) * 64 + (((ks * 4 + quad) ^ psw) * 8)];
        if (st) stageB(kt + 2, sb);
        __builtin_amdgcn_s_barrier();
        __builtin_amdgcn_sched_barrier(0);
        __builtin_amdgcn_s_setprio(1);
#pragma unroll
        for (int mp = 0; mp < 2; mp++)
#pragma unroll
            for (int np = 0; np < 2; np++)
#pragma unroll
                for (int ks = 0; ks < 2; ks++)
                    acc[mp + 2][np + 2] = __builtin_amdgcn_mfma_f32_16x16x32_bf16(a[mp][ks], b1[np][ks], acc[mp + 2][np + 2], 0, 0, 0);
        __builtin_amdgcn_s_setprio(0);
        __builtin_amdgcn_s_barrier();
        __builtin_amdgcn_sched_barrier(0);

        // ---- P4: MFMA acc[2,3][0,1] (reuse a=m23, b0=n01); per-K-tile checkpoint
        __builtin_amdgcn_s_setprio(1);
#pragma unroll
        for (int mp = 0; mp < 2; mp++)
#pragma unroll
            for (int np = 0; np < 2; np++)
#pragma unroll
                for (int ks = 0; ks < 2; ks++)
                    acc[mp + 2][np] = __builtin_amdgcn_mfma_f32_16x16x32_bf16(a[mp][ks], b0[np][ks], acc[mp + 2][np], 0, 0, 0);
        __builtin_amdgcn_s_setprio(0);
        if (kt < KT16 - 2)       asm volatile("s_waitcnt vmcnt(6)" ::: "memory");
        else if (kt == KT16 - 2) asm volatile("s_waitcnt vmcnt(0)" ::: "memory");
        if (kt < KT16 - 1) {
            __builtin_amdgcn_s_barrier();
            __builtin_amdgcn_sched_barrier(0);
        }
    }

    // epilogue: route n<1024 -> Q, else K (BN=128 -> per-block uniform)
    bool isQ = (n0 < 1024);
    bf16* Cd = isQ ? Qo : Ko;
    int nb = isQ ? n0 : (n0 - 1024);
#pragma unroll
    for (int mf = 0; mf < 4; mf++)
#pragma unroll
        for (int nf = 0; nf < 4; nf++) {
            int gr = m0 + wm * 64 + mf * 16 + quad * 4;
            int gc = nb + wn * 64 + nf * 16 + cl;
#pragma unroll
            for (int rg = 0; rg < 4; rg++)
                Cd[(size_t)(gr + rg) * HH + gc] = (bf16)acc[mf][nf][rg];
        }
}

// ------- 128x128 bf16 GEMM, m97-style global_load_lds staging -------
// Unpadded 128x32 tiles; source-column swizzle (chunk x ^ ((r>>1)&3)) makes
// frag ds_read_b128 2-way bank-aliased (free). tv=1 -> V^T layout [b][h][d][T].
__global__ __launch_bounds__(256) void gemm_bf128_k(const bf16* __restrict__ A,
                                                    const bf16* __restrict__ W,
                                                    bf16* __restrict__ C, int tv) {
    const int K = HH, N = HH;
    __shared__ __align__(16) bf16 As[128 * 32];
    __shared__ __align__(16) bf16 Ws[128 * 32];
    int m0 = blockIdx.x * 128, n0 = blockIdx.y * 128;
    int t = threadIdx.x, lane = t & 63, w = t >> 6;
    int wm = w >> 1, wn = w & 1;
    int quad = lane >> 4, cl = lane & 15;
    int rA0 = w * 16 + (lane >> 2);                    // + i*64
    int xa = (((lane & 3) ^ ((lane >> 3) & 3)) * 8);   // swizzled source col
    char* AsB = (char*)As + w * 1024;
    char* WsB = (char*)Ws + w * 1024;
    int pc = (quad ^ ((cl >> 1) & 3)) * 8;             // frag phys chunk offset
    floatx4 acc[4][4] = {};
    for (int k0 = 0; k0 < K; k0 += 32) {
        __syncthreads();
#pragma unroll
        for (int i = 0; i < 2; i++) {
            gl2lds16(&A[(size_t)(m0 + rA0 + i * 64) * K + k0 + xa], AsB + i * 4096);
            gl2lds16(&W[(size_t)(n0 + rA0 + i * 64) * K + k0 + xa], WsB + i * 4096);
        }
        __syncthreads();
        bf16x8 af[4], bfr[4];
#pragma unroll
        for (int i = 0; i < 4; i++) af[i]  = *(const bf16x8*)&As[(wm * 64 + i * 16 + cl) * 32 + pc];
#pragma unroll
        for (int j = 0; j < 4; j++) bfr[j] = *(const bf16x8*)&Ws[(wn * 64 + j * 16 + cl) * 32 + pc];
#pragma unroll
        for (int i = 0; i < 4; i++)
#pragma unroll
            for (int j = 0; j < 4; j++)
                acc[i][j] = __builtin_amdgcn_mfma_f32_16x16x32_bf16(af[i], bfr[j], acc[i][j], 0, 0, 0);
    }
#pragma unroll
    for (int i = 0; i < 4; i++)
#pragma unroll
        for (int j = 0; j < 4; j++) {
            int gr = m0 + wm * 64 + i * 16 + quad * 4;
            int gc = n0 + wn * 64 + j * 16 + cl;
            if (!tv) {
#pragma unroll
                for (int rg = 0; rg < 4; rg++)
                    C[(size_t)(gr + rg) * N + gc] = (bf16)acc[i][j][rg];
            } else {
                int bb2 = gr >> 11, tt2 = gr & 2047;
                int hh2 = gc >> 7,  dd2 = gc & 127;
                bf16x4 o4;
#pragma unroll
                for (int rg = 0; rg < 4; rg++) o4[rg] = (bf16)acc[i][j][rg];
                *(bf16x4*)&C[((size_t)(bb2 * NHEADS + hh2) * HDIM + dd2) * TT + tt2] = o4;
            }
        }
}

// ------- 128x128 final GEMM (same staging): out_f32 = A_bf16 * Wb_bf16^T + R_f32 -------
__global__ __launch_bounds__(256) void gemm_finbf_k(const bf16* __restrict__ A,
                                                    const bf16* __restrict__ W,
                                                    const float* __restrict__ R,
                                                    float* __restrict__ C) {
    const int K = HH, N = HH;
    __shared__ __align__(16) bf16 As[128 * 32];
    __shared__ __align__(16) bf16 Ws[128 * 32];
    int m0 = blockIdx.x * 128, n0 = blockIdx.y * 128;
    int t = threadIdx.x, lane = t & 63, w = t >> 6;
    int wm = w >> 1, wn = w & 1;
    int quad = lane >> 4, cl = lane & 15;
    int rA0 = w * 16 + (lane >> 2);
    int xa = (((lane & 3) ^ ((lane >> 3) & 3)) * 8);
    char* AsB = (char*)As + w * 1024;
    char* WsB = (char*)Ws + w * 1024;
    int pc = (quad ^ ((cl >> 1) & 3)) * 8;
    floatx4 acc[4][4] = {};
    for (int k0 = 0; k0 < K; k0 += 32) {
        __syncthreads();
#pragma unroll
        for (int i = 0; i < 2; i++) {
            gl2lds16(&A[(size_t)(m0 + rA0 + i * 64) * K + k0 + xa], AsB + i * 4096);
            gl2lds16(&W[(size_t)(n0 + rA0 + i * 64) * K + k0 + xa], WsB + i * 4096);
        }
        __syncthreads();
        bf16x8 af[4], bfr[4];
#pragma unroll
        for (int i = 0; i < 4; i++) af[i]  = *(const bf16x8*)&As[(wm * 64 + i * 16 + cl) * 32 + pc];
#pragma unroll
        for (int j = 0; j < 4; j++) bfr[j] = *(const bf16x8*)&Ws[(wn * 64 + j * 16 + cl) * 32 + pc];
#pragma unroll
        for (int i = 0; i < 4; i++)
#pragma unroll
            for (int j = 0; j < 4; j++)
                acc[i][j] = __builtin_amdgcn_mfma_f32_16x16x32_bf16(af[i], bfr[j], acc[i][j], 0, 0, 0);
    }
#pragma unroll
    for (int i = 0; i < 4; i++)
#pragma unroll
        for (int j = 0; j < 4; j++)
#pragma unroll
            for (int rg = 0; rg < 4; rg++) {
                int gr = m0 + wm * 64 + i * 16 + quad * 4 + rg;
                int gc = n0 + wn * 64 + j * 16 + cl;
                C[(size_t)gr * N + gc] = acc[i][j][rg] + R[(size_t)gr * N + gc];
            }
}

// ---- Flash attention (causal): 128-row Q tile, Q frags from global, dbuf DMA K/V ----
// Single barrier per kv-tile: DMA for kt+1 issued at top of iter kt into the other
// buffer, drains at the end-of-iter barrier. Unpadded K (64x128) / V (128x64) tiles
// with source-swizzle (K: x^((r>>1)&7), V: x^(r&7)) -> 2-way-aliased frag reads.
// V pre-transposed [b][h][d][T]. O aliases Q (single-owner region per block).
// setprio(1) wraps the S and PV MFMA clusters (T5).
__global__ __launch_bounds__(256) void attn_k(const bf16* __restrict__ Q,
                                              const bf16* __restrict__ Kg,
                                              const bf16* __restrict__ Vt,
                                              bf16* __restrict__ O) {
    __shared__ __align__(16) bf16 Ks2[2][64 * 128];   // 2x16384 B
    __shared__ __align__(16) bf16 Vs2[2][128 * 64];   // 2x16384 B -> 65536 B total

    int qt = gridDim.x - 1 - blockIdx.x;  // longest blocks first
    int h = blockIdx.y, b = blockIdx.z;
    int t = threadIdx.x, lane = t & 63, w = t >> 6;
    int quad = lane >> 4, cl = lane & 15;
    size_t rowbase = (size_t)b * TT;
    int q0 = qt * 128;
    size_t hcol = (size_t)h * HDIM;
    size_t vtbase = (size_t)(b * NHEADS + h) * HDIM * TT;

    // Q fragments straight from global (one-time; L2-warm)
    bf16x8 qf[4][2];
#pragma unroll
    for (int kk = 0; kk < 4; kk++)
#pragma unroll
        for (int g = 0; g < 2; g++)
            qf[kk][g] = *(const bf16x8*)&Q[(rowbase + q0 + w * 32 + g * 16 + cl) * HH + hcol + kk * 32 + quad * 8];

    auto stage = [&](int ktf, int bb) {
        const bf16* kbase = &Kg[(rowbase + (size_t)ktf * 64) * HH + hcol];
        const bf16* vbase = &Vt[vtbase + (size_t)ktf * 64];
#pragma unroll
        for (int i = 0; i < 4; i++) {
            int rk = w * 16 + i * 4 + (lane >> 4);
            int xk = ((lane & 15) ^ ((rk >> 1) & 7)) * 8;
            gl2lds16(kbase + (size_t)rk * HH + xk, (char*)&Ks2[bb][0] + (w * 4 + i) * 1024);
            int rv = w * 32 + i * 8 + (lane >> 3);
            int xv = ((lane & 7) ^ (rv & 7)) * 8;
            gl2lds16(vbase + (size_t)rv * TT + xv, (char*)&Vs2[bb][0] + (w * 4 + i) * 1024);
        }
    };

    float m_i[2] = {-1e30f, -1e30f}, l_i[2] = {0.f, 0.f};
    floatx4 acc[8][2] = {};
    const float scale = 0.08838834764831845f;  // 1/sqrt(128)
    int kswz = ((cl >> 1) & 7);
    int vswz = (cl & 7);

    stage(0, 0);
    int ktmax = 2 * qt + 1;
    int p = 0;
    for (int kt = 0; kt <= ktmax; kt++) {
        if (kt == 0) __syncthreads();          // drain initial DMA
        if (kt < ktmax) stage(kt + 1, p ^ 1);  // in flight across whole body

        // S^T: A = K-frag (shared by both q-groups), B = Q-frag
        floatx4 sacc[2][4] = {};
        __builtin_amdgcn_s_setprio(1);
#pragma unroll
        for (int kk = 0; kk < 4; kk++)
#pragma unroll
            for (int jj = 0; jj < 4; jj++) {
                bf16x8 ak = *(const bf16x8*)&Ks2[p][(jj * 16 + cl) * 128 + ((kk * 4 + quad) ^ kswz) * 8];
                sacc[0][jj] = __builtin_amdgcn_mfma_f32_16x16x32_bf16(ak, qf[kk][0], sacc[0][jj], 0, 0, 0);
                sacc[1][jj] = __builtin_amdgcn_mfma_f32_16x16x32_bf16(ak, qf[kk][1], sacc[1][jj], 0, 0, 0);
            }
        __builtin_amdgcn_s_setprio(0);

        float pp[2][4][4], alpha[2];
        bool diag = (kt >= 2 * qt);
#pragma unroll
        for (int g = 0; g < 2; g++) {
            int qglob = q0 + w * 32 + g * 16 + cl;
            float mx = -1e30f;
#pragma unroll
            for (int jj = 0; jj < 4; jj++)
#pragma unroll
                for (int rg = 0; rg < 4; rg++) {
                    float sv = sacc[g][jj][rg] * scale;
                    if (diag && (kt * 64 + jj * 16 + quad * 4 + rg) > qglob) sv = -1e30f;
                    pp[g][jj][rg] = sv;
                    mx = fmaxf(mx, sv);
                }
            mx = fmaxf(mx, __shfl_xor(mx, 16));
            mx = fmaxf(mx, __shfl_xor(mx, 32));
            float mn = fmaxf(m_i[g], mx);
            alpha[g] = __expf(m_i[g] - mn);
            m_i[g] = mn;
            float sum = 0.f;
#pragma unroll
            for (int jj = 0; jj < 4; jj++)
#pragma unroll
                for (int rg = 0; rg < 4; rg++) {
                    float pe = __expf(pp[g][jj][rg] - mn);
                    pp[g][jj][rg] = pe;
                    sum += pe;
                }
            sum += __shfl_xor(sum, 16);
            sum += __shfl_xor(sum, 32);
            l_i[g] = l_i[g] * alpha[g] + sum;
        }

        int pk[2][4][2];
#pragma unroll
        for (int g = 0; g < 2; g++)
#pragma unroll
            for (int jj = 0; jj < 4; jj++) {
                union { bf16x4 v; int i2[2]; } u;
#pragma unroll
                for (int rg = 0; rg < 4; rg++) u.v[rg] = (bf16)pp[g][jj][rg];
                pk[g][jj][0] = u.i2[0];
                pk[g][jj][1] = u.i2[1];
            }
#pragma unroll
        for (int nt = 0; nt < 8; nt++) {
            acc[nt][0] *= alpha[0];
            acc[nt][1] *= alpha[1];
        }

        int La = ((2 * quad) & 3) * 16 + cl;
        int Lb = ((2 * quad + 1) & 3) * 16 + cl;
        bool hi = (quad >> 1) & 1;
#pragma unroll
        for (int kti = 0; kti < 2; kti++) {
            int j0 = kti * 2, j1 = kti * 2 + 1;
            union { bf16x8 v; int i4[4]; } pu[2];
#pragma unroll
            for (int g = 0; g < 2; g++) {
                int a0x = __shfl(pk[g][j0][0], La), a0y = __shfl(pk[g][j0][1], La);
                int a1x = __shfl(pk[g][j1][0], La), a1y = __shfl(pk[g][j1][1], La);
                int b0x = __shfl(pk[g][j0][0], Lb), b0y = __shfl(pk[g][j0][1], Lb);
                int b1x = __shfl(pk[g][j1][0], Lb), b1y = __shfl(pk[g][j1][1], Lb);
                pu[g].i4[0] = hi ? a1x : a0x;
                pu[g].i4[1] = hi ? a1y : a0y;
                pu[g].i4[2] = hi ? b1x : b0x;
                pu[g].i4[3] = hi ? b1y : b0y;
            }
            __builtin_amdgcn_s_setprio(1);
#pragma unroll
            for (int nt = 0; nt < 8; nt++) {
                bf16x8 av = *(const bf16x8*)&Vs2[p][(nt * 16 + cl) * 64 + ((kti * 4 + quad) ^ vswz) * 8];
                acc[nt][0] = __builtin_amdgcn_mfma_f32_16x16x32_bf16(av, pu[0].v, acc[nt][0], 0, 0, 0);
                acc[nt][1] = __builtin_amdgcn_mfma_f32_16x16x32_bf16(av, pu[1].v, acc[nt][1], 0, 0, 0);
            }
            __builtin_amdgcn_s_setprio(0);
        }
        __syncthreads();   // drains this iter's DMA; all reads of buf p done
        p ^= 1;
    }

    float linv[2] = {1.f / l_i[0], 1.f / l_i[1]};
#pragma unroll
    for (int g = 0; g < 2; g++)
#pragma unroll
        for (int nt = 0; nt < 8; nt++) {
            bf16x4 o4;
#pragma unroll
            for (int rg = 0; rg < 4; rg++) o4[rg] = (bf16)(acc[nt][g][rg] * linv[g]);
            *(bf16x4*)&O[(rowbase + q0 + w * 32 + g * 16 + cl) * HH + hcol + nt * 16 + quad * 4] = o4;
        }
}

extern "C" void kernel_launch(void* const* d_in, const int* in_sizes, int n_in,
                              void* d_out, int out_size, void* d_ws, size_t ws_size,
                              hipStream_t stream) {
    const float* x     = (const float*)d_in[0];
    const float* gamma = (const float*)d_in[1];
    const float* beta  = (const float*)d_in[2];
    const float* Wq    = (const float*)d_in[3];
    const float* Wk    = (const float*)d_in[4];
    const float* Wv    = (const float*)d_in[5];
    const float* Wo    = (const float*)d_in[6];
    float* out = (float*)d_out;

    const size_t NELEM = (size_t)MROWS * HH;
    // ws (35.7 MB): Qb bf16 + Vb bf16 + Wslot bf16 (2.1 MB).
    // Wqk (4.2 MB, Q and K weights concatenated) lives at the Vb region — Vb is not
    // produced until after the fused QK GEMM, so the regions never overlap in time.
    // d_out (33.5 MB f32): Kb bf16 + xn bf16 — dead before final GEMM writes.
    bf16* Qb    = (bf16*)d_ws;
    bf16* Vb    = Qb + NELEM;          // V^T layout [b][h][d][T]
    bf16* Wslot = Vb + NELEM;
    bf16* Wqk   = Vb;                  // 2048x1024 bf16, transient
    bf16* Kb    = (bf16*)d_out;
    bf16* xnb   = (bf16*)d_out + NELEM;

    ln_k<<<MROWS, 256, 0, stream>>>(x, gamma, beta, xnb);
    convw_k<<<HH * HH / 1024, 256, 0, stream>>>(Wq, Wqk);
    convw_k<<<HH * HH / 1024, 256, 0, stream>>>(Wk, Wqk + (size_t)HH * HH);
    gemm_qk8_k<<<512, 512, 0, stream>>>(xnb, Wqk, Qb, Kb);
    dim3 gg(MROWS / 128, HH / 128);
    convw_k<<<HH * HH / 1024, 256, 0, stream>>>(Wv, Wslot);
    gemm_bf128_k<<<gg, 256, 0, stream>>>(xnb, Wslot, Vb, 1);
    attn_k<<<dim3(TT / 128, NHEADS, BB), 256, 0, stream>>>(Qb, Kb, Vb, Qb);
    convw_k<<<HH * HH / 1024, 256, 0, stream>>>(Wo, Wslot);
    gemm_finbf_k<<<gg, 256, 0, stream>>>(Qb, Wslot, x, out);
}

// Round 3
// 393.605 us; speedup vs baseline: 1.0088x; 1.0088x over previous
//
#include <hip/hip_runtime.h>
#include <hip/hip_bf16.h>

#define HH 1024
#define NHEADS 8
#define HDIM 128
#define BB 4
#define TT 2048
#define MROWS (BB*TT)   // 8192

typedef __bf16 bf16;
typedef __bf16 bf16x4 __attribute__((ext_vector_type(4)));
typedef __bf16 bf16x8 __attribute__((ext_vector_type(8)));
typedef float floatx4 __attribute__((ext_vector_type(4)));

// async global->LDS DMA, 16B per lane; lds dest = wave-uniform base + lane*16
__device__ __forceinline__ void gl2lds16(const void* g, void* l) {
    __builtin_amdgcn_global_load_lds(
        (const __attribute__((address_space(1))) unsigned int*)g,
        (__attribute__((address_space(3))) unsigned int*)l, 16, 0, 0);
}

// ---------------- LayerNorm: one block per row, f32 in -> bf16 out ----------------
__global__ __launch_bounds__(256) void ln_k(const float* __restrict__ x,
                                            const float* __restrict__ g,
                                            const float* __restrict__ be,
                                            bf16* __restrict__ xn) {
    int row = blockIdx.x;
    int t = threadIdx.x;
    float4 v4 = ((const float4*)(x + (size_t)row * HH))[t];
    const float* v = (const float*)&v4;
    float s = v[0] + v[1] + v[2] + v[3];
    float s2 = v[0]*v[0] + v[1]*v[1] + v[2]*v[2] + v[3]*v[3];
#pragma unroll
    for (int off = 32; off > 0; off >>= 1) {
        s  += __shfl_down(s,  off);
        s2 += __shfl_down(s2, off);
    }
    __shared__ float red[8];
    if ((t & 63) == 0) { red[t >> 6] = s; red[(t >> 6) + 4] = s2; }
    __syncthreads();
    s  = red[0] + red[1] + red[2] + red[3];
    s2 = red[4] + red[5] + red[6] + red[7];
    float mu  = s * (1.f / HH);
    float var = s2 * (1.f / HH) - mu * mu;
    float rs  = rsqrtf(var + 1e-5f);
    float4 g4 = ((const float4*)g)[t];
    float4 b4 = ((const float4*)be)[t];
    const float* gv = (const float*)&g4;
    const float* bv = (const float*)&b4;
    bf16x4 o;
#pragma unroll
    for (int z = 0; z < 4; z++) o[z] = (bf16)((v[z] - mu) * rs * gv[z] + bv[z]);
    ((bf16x4*)(xn + (size_t)row * HH))[t] = o;
}

// ---------------- Weight convert f32 -> bf16 (1024x1024) ----------------
__global__ __launch_bounds__(256) void convw_k(const float* __restrict__ W,
                                               bf16* __restrict__ Wb) {
    int idx = blockIdx.x * 256 + threadIdx.x;
    float4 v4 = ((const float4*)W)[idx];
    const float* v = (const float*)&v4;
    bf16x4 o;
#pragma unroll
    for (int z = 0; z < 4; z++) o[z] = (bf16)v[z];
    ((bf16x4*)Wb)[idx] = o;
}

// ------- 128x128 bf16 GEMM, m97-style global_load_lds staging -------
// Unpadded 128x32 tiles; source-column swizzle (chunk x ^ ((r>>1)&3)) makes
// frag ds_read_b128 2-way bank-aliased (free). tv=1 -> V^T layout [b][h][d][T].
__global__ __launch_bounds__(256) void gemm_bf128_k(const bf16* __restrict__ A,
                                                    const bf16* __restrict__ W,
                                                    bf16* __restrict__ C, int tv) {
    const int K = HH, N = HH;
    __shared__ __align__(16) bf16 As[128 * 32];
    __shared__ __align__(16) bf16 Ws[128 * 32];
    int m0 = blockIdx.x * 128, n0 = blockIdx.y * 128;
    int t = threadIdx.x, lane = t & 63, w = t >> 6;
    int wm = w >> 1, wn = w & 1;
    int quad = lane >> 4, cl = lane & 15;
    int rA0 = w * 16 + (lane >> 2);                    // + i*64
    int xa = (((lane & 3) ^ ((lane >> 3) & 3)) * 8);   // swizzled source col
    char* AsB = (char*)As + w * 1024;
    char* WsB = (char*)Ws + w * 1024;
    int pc = (quad ^ ((cl >> 1) & 3)) * 8;             // frag phys chunk offset
    floatx4 acc[4][4] = {};
    for (int k0 = 0; k0 < K; k0 += 32) {
        __syncthreads();
#pragma unroll
        for (int i = 0; i < 2; i++) {
            gl2lds16(&A[(size_t)(m0 + rA0 + i * 64) * K + k0 + xa], AsB + i * 4096);
            gl2lds16(&W[(size_t)(n0 + rA0 + i * 64) * K + k0 + xa], WsB + i * 4096);
        }
        __syncthreads();
        bf16x8 af[4], bfr[4];
#pragma unroll
        for (int i = 0; i < 4; i++) af[i]  = *(const bf16x8*)&As[(wm * 64 + i * 16 + cl) * 32 + pc];
#pragma unroll
        for (int j = 0; j < 4; j++) bfr[j] = *(const bf16x8*)&Ws[(wn * 64 + j * 16 + cl) * 32 + pc];
#pragma unroll
        for (int i = 0; i < 4; i++)
#pragma unroll
            for (int j = 0; j < 4; j++)
                acc[i][j] = __builtin_amdgcn_mfma_f32_16x16x32_bf16(af[i], bfr[j], acc[i][j], 0, 0, 0);
    }
#pragma unroll
    for (int i = 0; i < 4; i++)
#pragma unroll
        for (int j = 0; j < 4; j++) {
            int gr = m0 + wm * 64 + i * 16 + quad * 4;
            int gc = n0 + wn * 64 + j * 16 + cl;
            if (!tv) {
#pragma unroll
                for (int rg = 0; rg < 4; rg++)
                    C[(size_t)(gr + rg) * N + gc] = (bf16)acc[i][j][rg];
            } else {
                int bb2 = gr >> 11, tt2 = gr & 2047;
                int hh2 = gc >> 7,  dd2 = gc & 127;
                bf16x4 o4;
#pragma unroll
                for (int rg = 0; rg < 4; rg++) o4[rg] = (bf16)acc[i][j][rg];
                *(bf16x4*)&C[((size_t)(bb2 * NHEADS + hh2) * HDIM + dd2) * TT + tt2] = o4;
            }
        }
}

// ------- 128x128 final GEMM (same staging): out_f32 = A_bf16 * Wb_bf16^T + R_f32 -------
__global__ __launch_bounds__(256) void gemm_finbf_k(const bf16* __restrict__ A,
                                                    const bf16* __restrict__ W,
                                                    const float* __restrict__ R,
                                                    float* __restrict__ C) {
    const int K = HH, N = HH;
    __shared__ __align__(16) bf16 As[128 * 32];
    __shared__ __align__(16) bf16 Ws[128 * 32];
    int m0 = blockIdx.x * 128, n0 = blockIdx.y * 128;
    int t = threadIdx.x, lane = t & 63, w = t >> 6;
    int wm = w >> 1, wn = w & 1;
    int quad = lane >> 4, cl = lane & 15;
    int rA0 = w * 16 + (lane >> 2);
    int xa = (((lane & 3) ^ ((lane >> 3) & 3)) * 8);
    char* AsB = (char*)As + w * 1024;
    char* WsB = (char*)Ws + w * 1024;
    int pc = (quad ^ ((cl >> 1) & 3)) * 8;
    floatx4 acc[4][4] = {};
    for (int k0 = 0; k0 < K; k0 += 32) {
        __syncthreads();
#pragma unroll
        for (int i = 0; i < 2; i++) {
            gl2lds16(&A[(size_t)(m0 + rA0 + i * 64) * K + k0 + xa], AsB + i * 4096);
            gl2lds16(&W[(size_t)(n0 + rA0 + i * 64) * K + k0 + xa], WsB + i * 4096);
        }
        __syncthreads();
        bf16x8 af[4], bfr[4];
#pragma unroll
        for (int i = 0; i < 4; i++) af[i]  = *(const bf16x8*)&As[(wm * 64 + i * 16 + cl) * 32 + pc];
#pragma unroll
        for (int j = 0; j < 4; j++) bfr[j] = *(const bf16x8*)&Ws[(wn * 64 + j * 16 + cl) * 32 + pc];
#pragma unroll
        for (int i = 0; i < 4; i++)
#pragma unroll
            for (int j = 0; j < 4; j++)
                acc[i][j] = __builtin_amdgcn_mfma_f32_16x16x32_bf16(af[i], bfr[j], acc[i][j], 0, 0, 0);
    }
#pragma unroll
    for (int i = 0; i < 4; i++)
#pragma unroll
        for (int j = 0; j < 4; j++)
#pragma unroll
            for (int rg = 0; rg < 4; rg++) {
                int gr = m0 + wm * 64 + i * 16 + quad * 4 + rg;
                int gc = n0 + wn * 64 + j * 16 + cl;
                C[(size_t)gr * N + gc] = acc[i][j][rg] + R[(size_t)gr * N + gc];
            }
}

// ---- Flash attention (causal): 128-row Q tile, Q frags from global ----
// Occupancy-first revision: K double-buffered (2x16KB), V SINGLE-buffered (16KB)
// -> 48KB LDS -> 3 blocks/CU; __launch_bounds__(256,4) caps VGPR at 128 so the
// VGPR cliff (m69: waves halve >128) doesn't bind below LDS. Pipeline per iter:
//   [top] issue K(kt+1) DMA (dbuf; overlaps S+softmax)
//   S-MFMA on Ks2[p]; softmax; P repack
//   counted vmcnt(4) (V(kt) = oldest 4 loads resident; K(kt+1) stays in flight)
//   s_barrier + sched_barrier(0); PV on Vs
//   __syncthreads() (all Vs reads done; drains K(kt+1)); issue V(kt+1) DMA
// V(kt+1) DMA overlaps next iter's S+softmax. No setprio (unvalidated at this
// occupancy). Unpadded tiles with source swizzle (K: x^((r>>1)&7), V: x^(r&7)).
__global__ __launch_bounds__(256, 4) void attn_k(const bf16* __restrict__ Q,
                                                 const bf16* __restrict__ Kg,
                                                 const bf16* __restrict__ Vt,
                                                 bf16* __restrict__ O) {
    __shared__ __align__(16) bf16 Ks2[2][64 * 128];   // 2x16384 B
    __shared__ __align__(16) bf16 Vs[128 * 64];       // 16384 B  -> 49152 B total

    int qt = gridDim.x - 1 - blockIdx.x;  // longest blocks first
    int h = blockIdx.y, b = blockIdx.z;
    int t = threadIdx.x, lane = t & 63, w = t >> 6;
    int quad = lane >> 4, cl = lane & 15;
    size_t rowbase = (size_t)b * TT;
    int q0 = qt * 128;
    size_t hcol = (size_t)h * HDIM;
    size_t vtbase = (size_t)(b * NHEADS + h) * HDIM * TT;

    // Q fragments straight from global (one-time; L2-warm)
    bf16x8 qf[4][2];
#pragma unroll
    for (int kk = 0; kk < 4; kk++)
#pragma unroll
        for (int g = 0; g < 2; g++)
            qf[kk][g] = *(const bf16x8*)&Q[(rowbase + q0 + w * 32 + g * 16 + cl) * HH + hcol + kk * 32 + quad * 8];

    auto stageK = [&](int ktf, int bb) {
        const bf16* kbase = &Kg[(rowbase + (size_t)ktf * 64) * HH + hcol];
#pragma unroll
        for (int i = 0; i < 4; i++) {
            int rk = w * 16 + i * 4 + (lane >> 4);
            int xk = ((lane & 15) ^ ((rk >> 1) & 7)) * 8;
            gl2lds16(kbase + (size_t)rk * HH + xk, (char*)&Ks2[bb][0] + (w * 4 + i) * 1024);
        }
    };
    auto stageV = [&](int ktf) {
        const bf16* vbase = &Vt[vtbase + (size_t)ktf * 64];
#pragma unroll
        for (int i = 0; i < 4; i++) {
            int rv = w * 32 + i * 8 + (lane >> 3);
            int xv = ((lane & 7) ^ (rv & 7)) * 8;
            gl2lds16(vbase + (size_t)rv * TT + xv, (char*)&Vs[0] + (w * 4 + i) * 1024);
        }
    };

    float m_i[2] = {-1e30f, -1e30f}, l_i[2] = {0.f, 0.f};
    floatx4 acc[8][2] = {};
    const float scale = 0.08838834764831845f;  // 1/sqrt(128)
    int kswz = ((cl >> 1) & 7);
    int vswz = (cl & 7);

    stageK(0, 0);
    stageV(0);
    __syncthreads();                      // drain initial K(0)+V(0)
    __builtin_amdgcn_sched_barrier(0);

    int ktmax = 2 * qt + 1;
    int p = 0;
    for (int kt = 0; kt <= ktmax; kt++) {
        if (kt < ktmax) stageK(kt + 1, p ^ 1);   // in flight across S+softmax(+PV)

        // S^T: A = K-frag (shared by both q-groups), B = Q-frag
        floatx4 sacc[2][4] = {};
#pragma unroll
        for (int kk = 0; kk < 4; kk++)
#pragma unroll
            for (int jj = 0; jj < 4; jj++) {
                bf16x8 ak = *(const bf16x8*)&Ks2[p][(jj * 16 + cl) * 128 + ((kk * 4 + quad) ^ kswz) * 8];
                sacc[0][jj] = __builtin_amdgcn_mfma_f32_16x16x32_bf16(ak, qf[kk][0], sacc[0][jj], 0, 0, 0);
                sacc[1][jj] = __builtin_amdgcn_mfma_f32_16x16x32_bf16(ak, qf[kk][1], sacc[1][jj], 0, 0, 0);
            }

        float pp[2][4][4], alpha[2];
        bool diag = (kt >= 2 * qt);
#pragma unroll
        for (int g = 0; g < 2; g++) {
            int qglob = q0 + w * 32 + g * 16 + cl;
            float mx = -1e30f;
#pragma unroll
            for (int jj = 0; jj < 4; jj++)
#pragma unroll
                for (int rg = 0; rg < 4; rg++) {
                    float sv = sacc[g][jj][rg] * scale;
                    if (diag && (kt * 64 + jj * 16 + quad * 4 + rg) > qglob) sv = -1e30f;
                    pp[g][jj][rg] = sv;
                    mx = fmaxf(mx, sv);
                }
            mx = fmaxf(mx, __shfl_xor(mx, 16));
            mx = fmaxf(mx, __shfl_xor(mx, 32));
            float mn = fmaxf(m_i[g], mx);
            alpha[g] = __expf(m_i[g] - mn);
            m_i[g] = mn;
            float sum = 0.f;
#pragma unroll
            for (int jj = 0; jj < 4; jj++)
#pragma unroll
                for (int rg = 0; rg < 4; rg++) {
                    float pe = __expf(pp[g][jj][rg] - mn);
                    pp[g][jj][rg] = pe;
                    sum += pe;
                }
            sum += __shfl_xor(sum, 16);
            sum += __shfl_xor(sum, 32);
            l_i[g] = l_i[g] * alpha[g] + sum;
        }

        int pk[2][4][2];
#pragma unroll
        for (int g = 0; g < 2; g++)
#pragma unroll
            for (int jj = 0; jj < 4; jj++) {
                union { bf16x4 v; int i2[2]; } u;
#pragma unroll
                for (int rg = 0; rg < 4; rg++) u.v[rg] = (bf16)pp[g][jj][rg];
                pk[g][jj][0] = u.i2[0];
                pk[g][jj][1] = u.i2[1];
            }
#pragma unroll
        for (int nt = 0; nt < 8; nt++) {
            acc[nt][0] *= alpha[0];
            acc[nt][1] *= alpha[1];
        }

        // V-resident gate: V(kt) = oldest 4 outstanding loads. Counted wait keeps
        // K(kt+1) (newest 4) in flight; last iter has no K prefetch -> full drain.
        if (kt < ktmax) asm volatile("s_waitcnt vmcnt(4)" ::: "memory");
        else            asm volatile("s_waitcnt vmcnt(0)" ::: "memory");
        __builtin_amdgcn_s_barrier();
        __builtin_amdgcn_sched_barrier(0);

        int La = ((2 * quad) & 3) * 16 + cl;
        int Lb = ((2 * quad + 1) & 3) * 16 + cl;
        bool hi = (quad >> 1) & 1;
#pragma unroll
        for (int kti = 0; kti < 2; kti++) {
            int j0 = kti * 2, j1 = kti * 2 + 1;
            union { bf16x8 v; int i4[4]; } pu[2];
#pragma unroll
            for (int g = 0; g < 2; g++) {
                int a0x = __shfl(pk[g][j0][0], La), a0y = __shfl(pk[g][j0][1], La);
                int a1x = __shfl(pk[g][j1][0], La), a1y = __shfl(pk[g][j1][1], La);
                int b0x = __shfl(pk[g][j0][0], Lb), b0y = __shfl(pk[g][j0][1], Lb);
                int b1x = __shfl(pk[g][j1][0], Lb), b1y = __shfl(pk[g][j1][1], Lb);
                pu[g].i4[0] = hi ? a1x : a0x;
                pu[g].i4[1] = hi ? a1y : a0y;
                pu[g].i4[2] = hi ? b1x : b0x;
                pu[g].i4[3] = hi ? b1y : b0y;
            }
#pragma unroll
            for (int nt = 0; nt < 8; nt++) {
                bf16x8 av = *(const bf16x8*)&Vs[(nt * 16 + cl) * 64 + ((kti * 4 + quad) ^ vswz) * 8];
                acc[nt][0] = __builtin_amdgcn_mfma_f32_16x16x32_bf16(av, pu[0].v, acc[nt][0], 0, 0, 0);
                acc[nt][1] = __builtin_amdgcn_mfma_f32_16x16x32_bf16(av, pu[1].v, acc[nt][1], 0, 0, 0);
            }
        }

        if (kt < ktmax) {
            __syncthreads();              // all Vs reads done (also drains K(kt+1))
            stageV(kt + 1);               // overlaps next iter's S+softmax
        }
        p ^= 1;
    }

    float linv[2] = {1.f / l_i[0], 1.f / l_i[1]};
#pragma unroll
    for (int g = 0; g < 2; g++)
#pragma unroll
        for (int nt = 0; nt < 8; nt++) {
            bf16x4 o4;
#pragma unroll
            for (int rg = 0; rg < 4; rg++) o4[rg] = (bf16)(acc[nt][g][rg] * linv[g]);
            *(bf16x4*)&O[(rowbase + q0 + w * 32 + g * 16 + cl) * HH + hcol + nt * 16 + quad * 4] = o4;
        }
}

extern "C" void kernel_launch(void* const* d_in, const int* in_sizes, int n_in,
                              void* d_out, int out_size, void* d_ws, size_t ws_size,
                              hipStream_t stream) {
    const float* x     = (const float*)d_in[0];
    const float* gamma = (const float*)d_in[1];
    const float* beta  = (const float*)d_in[2];
    const float* Wq    = (const float*)d_in[3];
    const float* Wk    = (const float*)d_in[4];
    const float* Wv    = (const float*)d_in[5];
    const float* Wo    = (const float*)d_in[6];
    float* out = (float*)d_out;

    const size_t NELEM = (size_t)MROWS * HH;
    // ws (35.7 MB): Qb bf16 + Vb bf16 + Wslot bf16 (2.1 MB, converted per-GEMM).
    // d_out (33.5 MB f32): Kb bf16 + xn bf16 — dead before final GEMM writes.
    bf16* Qb    = (bf16*)d_ws;
    bf16* Vb    = Qb + NELEM;          // V^T layout [b][h][d][T]
    bf16* Wslot = Vb + NELEM;
    bf16* Kb    = (bf16*)d_out;
    bf16* xnb   = (bf16*)d_out + NELEM;

    ln_k<<<MROWS, 256, 0, stream>>>(x, gamma, beta, xnb);
    dim3 gg(MROWS / 128, HH / 128);
    convw_k<<<HH * HH / 1024, 256, 0, stream>>>(Wq, Wslot);
    gemm_bf128_k<<<gg, 256, 0, stream>>>(xnb, Wslot, Qb, 0);
    convw_k<<<HH * HH / 1024, 256, 0, stream>>>(Wk, Wslot);
    gemm_bf128_k<<<gg, 256, 0, stream>>>(xnb, Wslot, Kb, 0);
    convw_k<<<HH * HH / 1024, 256, 0, stream>>>(Wv, Wslot);
    gemm_bf128_k<<<gg, 256, 0, stream>>>(xnb, Wslot, Vb, 1);
    attn_k<<<dim3(TT / 128, NHEADS, BB), 256, 0, stream>>>(Qb, Kb, Vb, Qb);
    convw_k<<<HH * HH / 1024, 256, 0, stream>>>(Wo, Wslot);
    gemm_finbf_k<<<gg, 256, 0, stream>>>(Qb, Wslot, x, out);
}

// Round 4
// 351.816 us; speedup vs baseline: 1.1286x; 1.1188x over previous
//
#include <hip/hip_runtime.h>
#include <hip/hip_bf16.h>

#define HH 1024
#define NHEADS 8
#define HDIM 128
#define BB 4
#define TT 2048
#define MROWS (BB*TT)   // 8192

typedef __bf16 bf16;
typedef __bf16 bf16x4 __attribute__((ext_vector_type(4)));
typedef __bf16 bf16x8 __attribute__((ext_vector_type(8)));
typedef float floatx4 __attribute__((ext_vector_type(4)));

// async global->LDS DMA, 16B per lane; lds dest = wave-uniform base + lane*16
__device__ __forceinline__ void gl2lds16(const void* g, void* l) {
    __builtin_amdgcn_global_load_lds(
        (const __attribute__((address_space(1))) unsigned int*)g,
        (__attribute__((address_space(3))) unsigned int*)l, 16, 0, 0);
}

// ---------------- LayerNorm: one block per row, f32 in -> bf16 out ----------------
__global__ __launch_bounds__(256) void ln_k(const float* __restrict__ x,
                                            const float* __restrict__ g,
                                            const float* __restrict__ be,
                                            bf16* __restrict__ xn) {
    int row = blockIdx.x;
    int t = threadIdx.x;
    float4 v4 = ((const float4*)(x + (size_t)row * HH))[t];
    const float* v = (const float*)&v4;
    float s = v[0] + v[1] + v[2] + v[3];
    float s2 = v[0]*v[0] + v[1]*v[1] + v[2]*v[2] + v[3]*v[3];
#pragma unroll
    for (int off = 32; off > 0; off >>= 1) {
        s  += __shfl_down(s,  off);
        s2 += __shfl_down(s2, off);
    }
    __shared__ float red[8];
    if ((t & 63) == 0) { red[t >> 6] = s; red[(t >> 6) + 4] = s2; }
    __syncthreads();
    s  = red[0] + red[1] + red[2] + red[3];
    s2 = red[4] + red[5] + red[6] + red[7];
    float mu  = s * (1.f / HH);
    float var = s2 * (1.f / HH) - mu * mu;
    float rs  = rsqrtf(var + 1e-5f);
    float4 g4 = ((const float4*)g)[t];
    float4 b4 = ((const float4*)be)[t];
    const float* gv = (const float*)&g4;
    const float* bv = (const float*)&b4;
    bf16x4 o;
#pragma unroll
    for (int z = 0; z < 4; z++) o[z] = (bf16)((v[z] - mu) * rs * gv[z] + bv[z]);
    ((bf16x4*)(xn + (size_t)row * HH))[t] = o;
}

// ---------------- Weight convert f32 -> bf16 (1024x1024) ----------------
__global__ __launch_bounds__(256) void convw_k(const float* __restrict__ W,
                                               bf16* __restrict__ Wb) {
    int idx = blockIdx.x * 256 + threadIdx.x;
    float4 v4 = ((const float4*)W)[idx];
    const float* v = (const float*)&v4;
    bf16x4 o;
#pragma unroll
    for (int z = 0; z < 4; z++) o[z] = (bf16)v[z];
    ((bf16x4*)Wb)[idx] = o;
}

// ------- 128x128 bf16 GEMM, m97-style global_load_lds staging -------
// Unpadded 128x32 tiles; source-column swizzle (chunk x ^ ((r>>1)&3)) makes
// frag ds_read_b128 2-way bank-aliased (free). tv=1 -> V^T layout [b][h][d][T].
__global__ __launch_bounds__(256) void gemm_bf128_k(const bf16* __restrict__ A,
                                                    const bf16* __restrict__ W,
                                                    bf16* __restrict__ C, int tv) {
    const int K = HH, N = HH;
    __shared__ __align__(16) bf16 As[128 * 32];
    __shared__ __align__(16) bf16 Ws[128 * 32];
    int m0 = blockIdx.x * 128, n0 = blockIdx.y * 128;
    int t = threadIdx.x, lane = t & 63, w = t >> 6;
    int wm = w >> 1, wn = w & 1;
    int quad = lane >> 4, cl = lane & 15;
    int rA0 = w * 16 + (lane >> 2);                    // + i*64
    int xa = (((lane & 3) ^ ((lane >> 3) & 3)) * 8);   // swizzled source col
    char* AsB = (char*)As + w * 1024;
    char* WsB = (char*)Ws + w * 1024;
    int pc = (quad ^ ((cl >> 1) & 3)) * 8;             // frag phys chunk offset
    floatx4 acc[4][4] = {};
    for (int k0 = 0; k0 < K; k0 += 32) {
        __syncthreads();
#pragma unroll
        for (int i = 0; i < 2; i++) {
            gl2lds16(&A[(size_t)(m0 + rA0 + i * 64) * K + k0 + xa], AsB + i * 4096);
            gl2lds16(&W[(size_t)(n0 + rA0 + i * 64) * K + k0 + xa], WsB + i * 4096);
        }
        __syncthreads();
        bf16x8 af[4], bfr[4];
#pragma unroll
        for (int i = 0; i < 4; i++) af[i]  = *(const bf16x8*)&As[(wm * 64 + i * 16 + cl) * 32 + pc];
#pragma unroll
        for (int j = 0; j < 4; j++) bfr[j] = *(const bf16x8*)&Ws[(wn * 64 + j * 16 + cl) * 32 + pc];
#pragma unroll
        for (int i = 0; i < 4; i++)
#pragma unroll
            for (int j = 0; j < 4; j++)
                acc[i][j] = __builtin_amdgcn_mfma_f32_16x16x32_bf16(af[i], bfr[j], acc[i][j], 0, 0, 0);
    }
#pragma unroll
    for (int i = 0; i < 4; i++)
#pragma unroll
        for (int j = 0; j < 4; j++) {
            int gr = m0 + wm * 64 + i * 16 + quad * 4;
            int gc = n0 + wn * 64 + j * 16 + cl;
            if (!tv) {
#pragma unroll
                for (int rg = 0; rg < 4; rg++)
                    C[(size_t)(gr + rg) * N + gc] = (bf16)acc[i][j][rg];
            } else {
                int bb2 = gr >> 11, tt2 = gr & 2047;
                int hh2 = gc >> 7,  dd2 = gc & 127;
                bf16x4 o4;
#pragma unroll
                for (int rg = 0; rg < 4; rg++) o4[rg] = (bf16)acc[i][j][rg];
                *(bf16x4*)&C[((size_t)(bb2 * NHEADS + hh2) * HDIM + dd2) * TT + tt2] = o4;
            }
        }
}

// ------- 128x128 final GEMM (same staging): out_f32 = A_bf16 * Wb_bf16^T + R_f32 -------
__global__ __launch_bounds__(256) void gemm_finbf_k(const bf16* __restrict__ A,
                                                    const bf16* __restrict__ W,
                                                    const float* __restrict__ R,
                                                    float* __restrict__ C) {
    const int K = HH, N = HH;
    __shared__ __align__(16) bf16 As[128 * 32];
    __shared__ __align__(16) bf16 Ws[128 * 32];
    int m0 = blockIdx.x * 128, n0 = blockIdx.y * 128;
    int t = threadIdx.x, lane = t & 63, w = t >> 6;
    int wm = w >> 1, wn = w & 1;
    int quad = lane >> 4, cl = lane & 15;
    int rA0 = w * 16 + (lane >> 2);
    int xa = (((lane & 3) ^ ((lane >> 3) & 3)) * 8);
    char* AsB = (char*)As + w * 1024;
    char* WsB = (char*)Ws + w * 1024;
    int pc = (quad ^ ((cl >> 1) & 3)) * 8;
    floatx4 acc[4][4] = {};
    for (int k0 = 0; k0 < K; k0 += 32) {
        __syncthreads();
#pragma unroll
        for (int i = 0; i < 2; i++) {
            gl2lds16(&A[(size_t)(m0 + rA0 + i * 64) * K + k0 + xa], AsB + i * 4096);
            gl2lds16(&W[(size_t)(n0 + rA0 + i * 64) * K + k0 + xa], WsB + i * 4096);
        }
        __syncthreads();
        bf16x8 af[4], bfr[4];
#pragma unroll
        for (int i = 0; i < 4; i++) af[i]  = *(const bf16x8*)&As[(wm * 64 + i * 16 + cl) * 32 + pc];
#pragma unroll
        for (int j = 0; j < 4; j++) bfr[j] = *(const bf16x8*)&Ws[(wn * 64 + j * 16 + cl) * 32 + pc];
#pragma unroll
        for (int i = 0; i < 4; i++)
#pragma unroll
            for (int j = 0; j < 4; j++)
                acc[i][j] = __builtin_amdgcn_mfma_f32_16x16x32_bf16(af[i], bfr[j], acc[i][j], 0, 0, 0);
    }
#pragma unroll
    for (int i = 0; i < 4; i++)
#pragma unroll
        for (int j = 0; j < 4; j++)
#pragma unroll
            for (int rg = 0; rg < 4; rg++) {
                int gr = m0 + wm * 64 + i * 16 + quad * 4 + rg;
                int gc = n0 + wn * 64 + j * 16 + cl;
                C[(size_t)gr * N + gc] = acc[i][j][rg] + R[(size_t)gr * N + gc];
            }
}

// ---- Flash attention (causal), 64-row Q tiles: grid-parallelism revision ----
// r3 post-mortem: occupancy was GRID-limited (512 blocks x 4 waves = 25% cap,
// measured 6.3% time-avg). This version: Q tile 64 rows -> 1024 blocks, 3
// blocks/CU resident (LDS 48KB) + refill; per-wave serial work per iter halves
// (each wave owns 16 Q rows; all MFMA fragment layouts unchanged, g-dim dropped).
// Deep pipeline, no full vmcnt drain in loop (per-thread ledger, 4 loads/stage):
//   top:   stage K(kt+1) (dbuf)            [outstanding: K(kt) V(kt) K(kt+1)]
//   S-gate:  vmcnt(8)  [last iter: 4]  -> K(kt) resident;  barrier
//   S-MFMA + softmax + P repack
//   PV-gate: vmcnt(4)  [last iter: 0]  -> V(kt) resident;  barrier
//   PV
//   raw barrier (LDS reuse only, no drain); stage V(kt+1) (single buffer)
// K: 64x128 unpadded, source-swizzle x^((r>>1)&7); V^T tile 128x64, x^(r&7).
__global__ __launch_bounds__(256) void attn_k(const bf16* __restrict__ Q,
                                              const bf16* __restrict__ Kg,
                                              const bf16* __restrict__ Vt,
                                              bf16* __restrict__ O) {
    __shared__ __align__(16) bf16 Ks2[2][64 * 128];   // 2x16384 B
    __shared__ __align__(16) bf16 Vs[128 * 64];       // 16384 B -> 49152 B total

    int qt = gridDim.x - 1 - blockIdx.x;  // longest blocks first
    int h = blockIdx.y, b = blockIdx.z;
    int t = threadIdx.x, lane = t & 63, w = t >> 6;
    int quad = lane >> 4, cl = lane & 15;
    size_t rowbase = (size_t)b * TT;
    int q0 = qt * 64;
    size_t hcol = (size_t)h * HDIM;
    size_t vtbase = (size_t)(b * NHEADS + h) * HDIM * TT;

    // Q fragments straight from global (one-time; L2-warm). Wave owns rows
    // q0 + w*16 + cl (16 rows/wave).
    bf16x8 qf[4];
#pragma unroll
    for (int kk = 0; kk < 4; kk++)
        qf[kk] = *(const bf16x8*)&Q[(rowbase + q0 + w * 16 + cl) * HH + hcol + kk * 32 + quad * 8];

    auto stageK = [&](int ktf, int bb) {
        const bf16* kbase = &Kg[(rowbase + (size_t)ktf * 64) * HH + hcol];
#pragma unroll
        for (int i = 0; i < 4; i++) {
            int rk = w * 16 + i * 4 + (lane >> 4);
            int xk = ((lane & 15) ^ ((rk >> 1) & 7)) * 8;
            gl2lds16(kbase + (size_t)rk * HH + xk, (char*)&Ks2[bb][0] + (w * 4 + i) * 1024);
        }
    };
    auto stageV = [&](int ktf) {
        const bf16* vbase = &Vt[vtbase + (size_t)ktf * 64];
#pragma unroll
        for (int i = 0; i < 4; i++) {
            int rv = w * 32 + i * 8 + (lane >> 3);
            int xv = ((lane & 7) ^ (rv & 7)) * 8;
            gl2lds16(vbase + (size_t)rv * TT + xv, (char*)&Vs[0] + (w * 4 + i) * 1024);
        }
    };

    float m_i = -1e30f, l_i = 0.f;
    floatx4 acc[8] = {};
    const float scale = 0.08838834764831845f;  // 1/sqrt(128)
    int kswz = ((cl >> 1) & 7);
    int vswz = (cl & 7);
    int qglob = q0 + w * 16 + cl;

    stageK(0, 0);
    stageV(0);                         // no drain: loop gates handle residency

    int p = 0;
    for (int kt = 0; kt <= qt; kt++) {
        bool lastit = (kt == qt);
        if (!lastit) stageK(kt + 1, p ^ 1);

        // S-gate: K(kt) = oldest 4 outstanding loads (of 12; 8 on last iter)
        if (!lastit) asm volatile("s_waitcnt vmcnt(8)" ::: "memory");
        else         asm volatile("s_waitcnt vmcnt(4)" ::: "memory");
        __builtin_amdgcn_s_barrier();
        __builtin_amdgcn_sched_barrier(0);

        // S^T: A = K-frag (64 kv), B = Q-frag (16 q rows of this wave)
        floatx4 sacc[4] = {};
#pragma unroll
        for (int kk = 0; kk < 4; kk++)
#pragma unroll
            for (int jj = 0; jj < 4; jj++) {
                bf16x8 ak = *(const bf16x8*)&Ks2[p][(jj * 16 + cl) * 128 + ((kk * 4 + quad) ^ kswz) * 8];
                sacc[jj] = __builtin_amdgcn_mfma_f32_16x16x32_bf16(ak, qf[kk], sacc[jj], 0, 0, 0);
            }

        float pp[4][4], alpha;
        {
            float mx = -1e30f;
#pragma unroll
            for (int jj = 0; jj < 4; jj++)
#pragma unroll
                for (int rg = 0; rg < 4; rg++) {
                    float sv = sacc[jj][rg] * scale;
                    if (lastit && (kt * 64 + jj * 16 + quad * 4 + rg) > qglob) sv = -1e30f;
                    pp[jj][rg] = sv;
                    mx = fmaxf(mx, sv);
                }
            mx = fmaxf(mx, __shfl_xor(mx, 16));
            mx = fmaxf(mx, __shfl_xor(mx, 32));
            float mn = fmaxf(m_i, mx);
            alpha = __expf(m_i - mn);
            m_i = mn;
            float sum = 0.f;
#pragma unroll
            for (int jj = 0; jj < 4; jj++)
#pragma unroll
                for (int rg = 0; rg < 4; rg++) {
                    float pe = __expf(pp[jj][rg] - mn);
                    pp[jj][rg] = pe;
                    sum += pe;
                }
            sum += __shfl_xor(sum, 16);
            sum += __shfl_xor(sum, 32);
            l_i = l_i * alpha + sum;
        }

        int pk[4][2];
#pragma unroll
        for (int jj = 0; jj < 4; jj++) {
            union { bf16x4 v; int i2[2]; } u;
#pragma unroll
            for (int rg = 0; rg < 4; rg++) u.v[rg] = (bf16)pp[jj][rg];
            pk[jj][0] = u.i2[0];
            pk[jj][1] = u.i2[1];
        }
#pragma unroll
        for (int nt = 0; nt < 8; nt++) acc[nt] *= alpha;

        // PV-gate: V(kt) resident; K(kt+1) (newest 4) stays in flight
        if (!lastit) asm volatile("s_waitcnt vmcnt(4)" ::: "memory");
        else         asm volatile("s_waitcnt vmcnt(0)" ::: "memory");
        __builtin_amdgcn_s_barrier();
        __builtin_amdgcn_sched_barrier(0);

        int La = ((2 * quad) & 3) * 16 + cl;
        int Lb = ((2 * quad + 1) & 3) * 16 + cl;
        bool hi = (quad >> 1) & 1;
#pragma unroll
        for (int kti = 0; kti < 2; kti++) {
            int j0 = kti * 2, j1 = kti * 2 + 1;
            union { bf16x8 v; int i4[4]; } pu;
            {
                int a0x = __shfl(pk[j0][0], La), a0y = __shfl(pk[j0][1], La);
                int a1x = __shfl(pk[j1][0], La), a1y = __shfl(pk[j1][1], La);
                int b0x = __shfl(pk[j0][0], Lb), b0y = __shfl(pk[j0][1], Lb);
                int b1x = __shfl(pk[j1][0], Lb), b1y = __shfl(pk[j1][1], Lb);
                pu.i4[0] = hi ? a1x : a0x;
                pu.i4[1] = hi ? a1y : a0y;
                pu.i4[2] = hi ? b1x : b0x;
                pu.i4[3] = hi ? b1y : b0y;
            }
#pragma unroll
            for (int nt = 0; nt < 8; nt++) {
                bf16x8 av = *(const bf16x8*)&Vs[(nt * 16 + cl) * 64 + ((kti * 4 + quad) ^ vswz) * 8];
                acc[nt] = __builtin_amdgcn_mfma_f32_16x16x32_bf16(av, pu.v, acc[nt], 0, 0, 0);
            }
        }

        if (!lastit) {
            __builtin_amdgcn_s_barrier();          // all Vs/Ks[p] reads done (no drain)
            __builtin_amdgcn_sched_barrier(0);
            stageV(kt + 1);                        // in flight across next S phase
        }
        p ^= 1;
    }

    float linv = 1.f / l_i;
#pragma unroll
    for (int nt = 0; nt < 8; nt++) {
        bf16x4 o4;
#pragma unroll
        for (int rg = 0; rg < 4; rg++) o4[rg] = (bf16)(acc[nt][rg] * linv);
        *(bf16x4*)&O[(rowbase + q0 + w * 16 + cl) * HH + hcol + nt * 16 + quad * 4] = o4;
    }
}

extern "C" void kernel_launch(void* const* d_in, const int* in_sizes, int n_in,
                              void* d_out, int out_size, void* d_ws, size_t ws_size,
                              hipStream_t stream) {
    const float* x     = (const float*)d_in[0];
    const float* gamma = (const float*)d_in[1];
    const float* beta  = (const float*)d_in[2];
    const float* Wq    = (const float*)d_in[3];
    const float* Wk    = (const float*)d_in[4];
    const float* Wv    = (const float*)d_in[5];
    const float* Wo    = (const float*)d_in[6];
    float* out = (float*)d_out;

    const size_t NELEM = (size_t)MROWS * HH;
    // ws (35.7 MB): Qb bf16 + Vb bf16 + Wslot bf16 (2.1 MB, converted per-GEMM).
    // d_out (33.5 MB f32): Kb bf16 + xn bf16 — dead before final GEMM writes.
    bf16* Qb    = (bf16*)d_ws;
    bf16* Vb    = Qb + NELEM;          // V^T layout [b][h][d][T]
    bf16* Wslot = Vb + NELEM;
    bf16* Kb    = (bf16*)d_out;
    bf16* xnb   = (bf16*)d_out + NELEM;

    ln_k<<<MROWS, 256, 0, stream>>>(x, gamma, beta, xnb);
    dim3 gg(MROWS / 128, HH / 128);
    convw_k<<<HH * HH / 1024, 256, 0, stream>>>(Wq, Wslot);
    gemm_bf128_k<<<gg, 256, 0, stream>>>(xnb, Wslot, Qb, 0);
    convw_k<<<HH * HH / 1024, 256, 0, stream>>>(Wk, Wslot);
    gemm_bf128_k<<<gg, 256, 0, stream>>>(xnb, Wslot, Kb, 0);
    convw_k<<<HH * HH / 1024, 256, 0, stream>>>(Wv, Wslot);
    gemm_bf128_k<<<gg, 256, 0, stream>>>(xnb, Wslot, Vb, 1);
    attn_k<<<dim3(TT / 64, NHEADS, BB), 256, 0, stream>>>(Qb, Kb, Vb, Qb);
    convw_k<<<HH * HH / 1024, 256, 0, stream>>>(Wo, Wslot);
    gemm_finbf_k<<<gg, 256, 0, stream>>>(Qb, Wslot, x, out);
}

// Round 5
// 288.759 us; speedup vs baseline: 1.3751x; 1.2184x over previous
//
#include <hip/hip_runtime.h>
#include <hip/hip_bf16.h>

#define HH 1024
#define NHEADS 8
#define HDIM 128
#define BB 4
#define TT 2048
#define MROWS (BB*TT)   // 8192

typedef __bf16 bf16;
typedef __bf16 bf16x4 __attribute__((ext_vector_type(4)));
typedef __bf16 bf16x8 __attribute__((ext_vector_type(8)));
typedef float floatx4 __attribute__((ext_vector_type(4)));

// async global->LDS DMA, 16B per lane; lds dest = wave-uniform base + lane*16
__device__ __forceinline__ void gl2lds16(const void* g, void* l) {
    __builtin_amdgcn_global_load_lds(
        (const __attribute__((address_space(1))) unsigned int*)g,
        (__attribute__((address_space(3))) unsigned int*)l, 16, 0, 0);
}

// ---------------- LayerNorm: one block per row, f32 in -> bf16 out ----------------
__global__ __launch_bounds__(256) void ln_k(const float* __restrict__ x,
                                            const float* __restrict__ g,
                                            const float* __restrict__ be,
                                            bf16* __restrict__ xn) {
    int row = blockIdx.x;
    int t = threadIdx.x;
    float4 v4 = ((const float4*)(x + (size_t)row * HH))[t];
    const float* v = (const float*)&v4;
    float s = v[0] + v[1] + v[2] + v[3];
    float s2 = v[0]*v[0] + v[1]*v[1] + v[2]*v[2] + v[3]*v[3];
#pragma unroll
    for (int off = 32; off > 0; off >>= 1) {
        s  += __shfl_down(s,  off);
        s2 += __shfl_down(s2, off);
    }
    __shared__ float red[8];
    if ((t & 63) == 0) { red[t >> 6] = s; red[(t >> 6) + 4] = s2; }
    __syncthreads();
    s  = red[0] + red[1] + red[2] + red[3];
    s2 = red[4] + red[5] + red[6] + red[7];
    float mu  = s * (1.f / HH);
    float var = s2 * (1.f / HH) - mu * mu;
    float rs  = rsqrtf(var + 1e-5f);
    float4 g4 = ((const float4*)g)[t];
    float4 b4 = ((const float4*)be)[t];
    const float* gv = (const float*)&g4;
    const float* bv = (const float*)&b4;
    bf16x4 o;
#pragma unroll
    for (int z = 0; z < 4; z++) o[z] = (bf16)((v[z] - mu) * rs * gv[z] + bv[z]);
    ((bf16x4*)(xn + (size_t)row * HH))[t] = o;
}

// ---------------- Weight convert f32 -> bf16 (1024x1024) ----------------
__global__ __launch_bounds__(256) void convw_k(const float* __restrict__ W,
                                               bf16* __restrict__ Wb) {
    int idx = blockIdx.x * 256 + threadIdx.x;
    float4 v4 = ((const float4*)W)[idx];
    const float* v = (const float*)&v4;
    bf16x4 o;
#pragma unroll
    for (int z = 0; z < 4; z++) o[z] = (bf16)v[z];
    ((bf16x4*)Wb)[idx] = o;
}

// ------- 128x128 bf16 GEMM, m97-style global_load_lds staging -------
// Unpadded 128x32 tiles; source-column swizzle (chunk x ^ ((r>>1)&3)) makes
// frag ds_read_b128 2-way bank-aliased (free). tv=1 -> V^T layout [b][h][d][T].
__global__ __launch_bounds__(256) void gemm_bf128_k(const bf16* __restrict__ A,
                                                    const bf16* __restrict__ W,
                                                    bf16* __restrict__ C, int tv) {
    const int K = HH, N = HH;
    __shared__ __align__(16) bf16 As[128 * 32];
    __shared__ __align__(16) bf16 Ws[128 * 32];
    int m0 = blockIdx.x * 128, n0 = blockIdx.y * 128;
    int t = threadIdx.x, lane = t & 63, w = t >> 6;
    int wm = w >> 1, wn = w & 1;
    int quad = lane >> 4, cl = lane & 15;
    int rA0 = w * 16 + (lane >> 2);                    // + i*64
    int xa = (((lane & 3) ^ ((lane >> 3) & 3)) * 8);   // swizzled source col
    char* AsB = (char*)As + w * 1024;
    char* WsB = (char*)Ws + w * 1024;
    int pc = (quad ^ ((cl >> 1) & 3)) * 8;             // frag phys chunk offset
    floatx4 acc[4][4] = {};
    for (int k0 = 0; k0 < K; k0 += 32) {
        __syncthreads();
#pragma unroll
        for (int i = 0; i < 2; i++) {
            gl2lds16(&A[(size_t)(m0 + rA0 + i * 64) * K + k0 + xa], AsB + i * 4096);
            gl2lds16(&W[(size_t)(n0 + rA0 + i * 64) * K + k0 + xa], WsB + i * 4096);
        }
        __syncthreads();
        bf16x8 af[4], bfr[4];
#pragma unroll
        for (int i = 0; i < 4; i++) af[i]  = *(const bf16x8*)&As[(wm * 64 + i * 16 + cl) * 32 + pc];
#pragma unroll
        for (int j = 0; j < 4; j++) bfr[j] = *(const bf16x8*)&Ws[(wn * 64 + j * 16 + cl) * 32 + pc];
#pragma unroll
        for (int i = 0; i < 4; i++)
#pragma unroll
            for (int j = 0; j < 4; j++)
                acc[i][j] = __builtin_amdgcn_mfma_f32_16x16x32_bf16(af[i], bfr[j], acc[i][j], 0, 0, 0);
    }
#pragma unroll
    for (int i = 0; i < 4; i++)
#pragma unroll
        for (int j = 0; j < 4; j++) {
            int gr = m0 + wm * 64 + i * 16 + quad * 4;
            int gc = n0 + wn * 64 + j * 16 + cl;
            if (!tv) {
#pragma unroll
                for (int rg = 0; rg < 4; rg++)
                    C[(size_t)(gr + rg) * N + gc] = (bf16)acc[i][j][rg];
            } else {
                int bb2 = gr >> 11, tt2 = gr & 2047;
                int hh2 = gc >> 7,  dd2 = gc & 127;
                bf16x4 o4;
#pragma unroll
                for (int rg = 0; rg < 4; rg++) o4[rg] = (bf16)acc[i][j][rg];
                *(bf16x4*)&C[((size_t)(bb2 * NHEADS + hh2) * HDIM + dd2) * TT + tt2] = o4;
            }
        }
}

// ------- 128x128 final GEMM (same staging): out_f32 = A_bf16 * Wb_bf16^T + R_f32 -------
__global__ __launch_bounds__(256) void gemm_finbf_k(const bf16* __restrict__ A,
                                                    const bf16* __restrict__ W,
                                                    const float* __restrict__ R,
                                                    float* __restrict__ C) {
    const int K = HH, N = HH;
    __shared__ __align__(16) bf16 As[128 * 32];
    __shared__ __align__(16) bf16 Ws[128 * 32];
    int m0 = blockIdx.x * 128, n0 = blockIdx.y * 128;
    int t = threadIdx.x, lane = t & 63, w = t >> 6;
    int wm = w >> 1, wn = w & 1;
    int quad = lane >> 4, cl = lane & 15;
    int rA0 = w * 16 + (lane >> 2);
    int xa = (((lane & 3) ^ ((lane >> 3) & 3)) * 8);
    char* AsB = (char*)As + w * 1024;
    char* WsB = (char*)Ws + w * 1024;
    int pc = (quad ^ ((cl >> 1) & 3)) * 8;
    floatx4 acc[4][4] = {};
    for (int k0 = 0; k0 < K; k0 += 32) {
        __syncthreads();
#pragma unroll
        for (int i = 0; i < 2; i++) {
            gl2lds16(&A[(size_t)(m0 + rA0 + i * 64) * K + k0 + xa], AsB + i * 4096);
            gl2lds16(&W[(size_t)(n0 + rA0 + i * 64) * K + k0 + xa], WsB + i * 4096);
        }
        __syncthreads();
        bf16x8 af[4], bfr[4];
#pragma unroll
        for (int i = 0; i < 4; i++) af[i]  = *(const bf16x8*)&As[(wm * 64 + i * 16 + cl) * 32 + pc];
#pragma unroll
        for (int j = 0; j < 4; j++) bfr[j] = *(const bf16x8*)&Ws[(wn * 64 + j * 16 + cl) * 32 + pc];
#pragma unroll
        for (int i = 0; i < 4; i++)
#pragma unroll
            for (int j = 0; j < 4; j++)
                acc[i][j] = __builtin_amdgcn_mfma_f32_16x16x32_bf16(af[i], bfr[j], acc[i][j], 0, 0, 0);
    }
#pragma unroll
    for (int i = 0; i < 4; i++)
#pragma unroll
        for (int j = 0; j < 4; j++)
#pragma unroll
            for (int rg = 0; rg < 4; rg++) {
                int gr = m0 + wm * 64 + i * 16 + quad * 4 + rg;
                int gc = n0 + wn * 64 + j * 16 + cl;
                C[(size_t)gr * N + gc] = acc[i][j][rg] + R[(size_t)gr * N + gc];
            }
}

// ---- Flash attention (causal), 64-row Q tiles: latency-schedule revision ----
// r4 post-mortem: ~4.8k cyc/wave-iter with near-zero overlap; V staged only
// softmax-ahead of its PV use (stall), and K/V streams sprayed across XCDs
// (L2 miss -> HBM-class DMA latency). This version:
//   * K SINGLE-buffered (16KB) + V DOUBLE-buffered (32KB) = 48KB (3 blocks/CU).
//     V(kt+1) staged at TOP of iter kt (full-iter cover); K(kt+1) staged right
//     after a post-S barrier (softmax+PV+top cover). S-gate vmcnt(4) proves
//     BOTH K(kt) and V(kt) resident (V older) -> PV needs NO vmcnt gate.
//     One vmcnt + 3 barriers per iter, every DMA ~1 iter of cover.
//     Ledger (4 loads/stage): at S-gate outstanding = V(kt),K(kt),V(kt+1) = 12
//     -> vmcnt(4). Last iter: 8 outstanding -> vmcnt(0).
//   * XCD-locality swizzle: 1-D grid 1024; wid&7 = XCD (round-robin assumption),
//     all 32 qt-blocks of one (b,h) share an XCD -> K+V (1MB) fits 4MB L2.
//     qt = 31-(idx>>2): long blocks first across all groups.
__global__ __launch_bounds__(256) void attn_k(const bf16* __restrict__ Q,
                                              const bf16* __restrict__ Kg,
                                              const bf16* __restrict__ Vt,
                                              bf16* __restrict__ O) {
    __shared__ __align__(16) bf16 Ks[64 * 128];       // 16384 B (single)
    __shared__ __align__(16) bf16 Vs2[2][128 * 64];   // 2x16384 B -> 49152 B total

    int wid = blockIdx.x;            // 1024 blocks
    int xcd = wid & 7;
    int idx = wid >> 3;              // 0..127
    int qt  = 31 - (idx >> 2);       // long blocks first, all groups
    int grp = (idx & 3) * 8 + xcd;   // 0..31 ; all qt of grp share an XCD
    int b = grp >> 3, h = grp & 7;

    int t = threadIdx.x, lane = t & 63, w = t >> 6;
    int quad = lane >> 4, cl = lane & 15;
    size_t rowbase = (size_t)b * TT;
    int q0 = qt * 64;
    size_t hcol = (size_t)h * HDIM;
    size_t vtbase = (size_t)(b * NHEADS + h) * HDIM * TT;

    // Q fragments straight from global (one-time; L2-warm). Wave owns rows
    // q0 + w*16 + cl (16 rows/wave).
    bf16x8 qf[4];
#pragma unroll
    for (int kk = 0; kk < 4; kk++)
        qf[kk] = *(const bf16x8*)&Q[(rowbase + q0 + w * 16 + cl) * HH + hcol + kk * 32 + quad * 8];

    auto stageK = [&](int ktf) {
        const bf16* kbase = &Kg[(rowbase + (size_t)ktf * 64) * HH + hcol];
#pragma unroll
        for (int i = 0; i < 4; i++) {
            int rk = w * 16 + i * 4 + (lane >> 4);
            int xk = ((lane & 15) ^ ((rk >> 1) & 7)) * 8;
            gl2lds16(kbase + (size_t)rk * HH + xk, (char*)&Ks[0] + (w * 4 + i) * 1024);
        }
    };
    auto stageV = [&](int ktf, int bb) {
        const bf16* vbase = &Vt[vtbase + (size_t)ktf * 64];
#pragma unroll
        for (int i = 0; i < 4; i++) {
            int rv = w * 32 + i * 8 + (lane >> 3);
            int xv = ((lane & 7) ^ (rv & 7)) * 8;
            gl2lds16(vbase + (size_t)rv * TT + xv, (char*)&Vs2[bb][0] + (w * 4 + i) * 1024);
        }
    };

    float m_i = -1e30f, l_i = 0.f;
    floatx4 acc[8] = {};
    const float scale = 0.08838834764831845f;  // 1/sqrt(128)
    int kswz = ((cl >> 1) & 7);
    int vswz = (cl & 7);
    int qglob = q0 + w * 16 + cl;

    stageV(0, 0);                   // oldest loads: V(0)
    stageK(0);                      // then K(0); loop gates handle residency

    int p = 0;
    for (int kt = 0; kt <= qt; kt++) {
        bool lastit = (kt == qt);
        if (!lastit) stageV(kt + 1, p ^ 1);   // full-iter cover before its PV

        // S-gate: wait K(kt) (forces V(kt) too, it's older); keep V(kt+1) in flight
        if (!lastit) asm volatile("s_waitcnt vmcnt(4)" ::: "memory");
        else         asm volatile("s_waitcnt vmcnt(0)" ::: "memory");
        __builtin_amdgcn_s_barrier();
        __builtin_amdgcn_sched_barrier(0);

        // S^T: A = K-frag (64 kv), B = Q-frag (16 q rows of this wave)
        floatx4 sacc[4] = {};
#pragma unroll
        for (int kk = 0; kk < 4; kk++)
#pragma unroll
            for (int jj = 0; jj < 4; jj++) {
                bf16x8 ak = *(const bf16x8*)&Ks[(jj * 16 + cl) * 128 + ((kk * 4 + quad) ^ kswz) * 8];
                sacc[jj] = __builtin_amdgcn_mfma_f32_16x16x32_bf16(ak, qf[kk], sacc[jj], 0, 0, 0);
            }

        // post-S: all waves' Ks reads done -> overwrite with K(kt+1); DMA covered
        // by softmax+PV+end-barrier+next-top.
        if (!lastit) {
            __builtin_amdgcn_s_barrier();
            __builtin_amdgcn_sched_barrier(0);
            stageK(kt + 1);
        }

        float pp[4][4], alpha;
        {
            float mx = -1e30f;
#pragma unroll
            for (int jj = 0; jj < 4; jj++)
#pragma unroll
                for (int rg = 0; rg < 4; rg++) {
                    float sv = sacc[jj][rg] * scale;
                    if (lastit && (kt * 64 + jj * 16 + quad * 4 + rg) > qglob) sv = -1e30f;
                    pp[jj][rg] = sv;
                    mx = fmaxf(mx, sv);
                }
            mx = fmaxf(mx, __shfl_xor(mx, 16));
            mx = fmaxf(mx, __shfl_xor(mx, 32));
            float mn = fmaxf(m_i, mx);
            alpha = __expf(m_i - mn);
            m_i = mn;
            float sum = 0.f;
#pragma unroll
            for (int jj = 0; jj < 4; jj++)
#pragma unroll
                for (int rg = 0; rg < 4; rg++) {
                    float pe = __expf(pp[jj][rg] - mn);
                    pp[jj][rg] = pe;
                    sum += pe;
                }
            sum += __shfl_xor(sum, 16);
            sum += __shfl_xor(sum, 32);
            l_i = l_i * alpha + sum;
        }

        int pk[4][2];
#pragma unroll
        for (int jj = 0; jj < 4; jj++) {
            union { bf16x4 v; int i2[2]; } u;
#pragma unroll
            for (int rg = 0; rg < 4; rg++) u.v[rg] = (bf16)pp[jj][rg];
            pk[jj][0] = u.i2[0];
            pk[jj][1] = u.i2[1];
        }
#pragma unroll
        for (int nt = 0; nt < 8; nt++) acc[nt] *= alpha;

        // PV: V(kt) proven resident at S-gate (no vmcnt, no extra barrier)
        int La = ((2 * quad) & 3) * 16 + cl;
        int Lb = ((2 * quad + 1) & 3) * 16 + cl;
        bool hi = (quad >> 1) & 1;
#pragma unroll
        for (int kti = 0; kti < 2; kti++) {
            int j0 = kti * 2, j1 = kti * 2 + 1;
            union { bf16x8 v; int i4[4]; } pu;
            {
                int a0x = __shfl(pk[j0][0], La), a0y = __shfl(pk[j0][1], La);
                int a1x = __shfl(pk[j1][0], La), a1y = __shfl(pk[j1][1], La);
                int b0x = __shfl(pk[j0][0], Lb), b0y = __shfl(pk[j0][1], Lb);
                int b1x = __shfl(pk[j1][0], Lb), b1y = __shfl(pk[j1][1], Lb);
                pu.i4[0] = hi ? a1x : a0x;
                pu.i4[1] = hi ? a1y : a0y;
                pu.i4[2] = hi ? b1x : b0x;
                pu.i4[3] = hi ? b1y : b0y;
            }
#pragma unroll
            for (int nt = 0; nt < 8; nt++) {
                bf16x8 av = *(const bf16x8*)&Vs2[p][(nt * 16 + cl) * 64 + ((kti * 4 + quad) ^ vswz) * 8];
                acc[nt] = __builtin_amdgcn_mfma_f32_16x16x32_bf16(av, pu.v, acc[nt], 0, 0, 0);
            }
        }

        // end barrier: next iter's top-stage overwrites Vs2[p] (read by this PV)
        if (!lastit) {
            __builtin_amdgcn_s_barrier();
            __builtin_amdgcn_sched_barrier(0);
        }
        p ^= 1;
    }

    float linv = 1.f / l_i;
#pragma unroll
    for (int nt = 0; nt < 8; nt++) {
        bf16x4 o4;
#pragma unroll
        for (int rg = 0; rg < 4; rg++) o4[rg] = (bf16)(acc[nt][rg] * linv);
        *(bf16x4*)&O[(rowbase + q0 + w * 16 + cl) * HH + hcol + nt * 16 + quad * 4] = o4;
    }
}

extern "C" void kernel_launch(void* const* d_in, const int* in_sizes, int n_in,
                              void* d_out, int out_size, void* d_ws, size_t ws_size,
                              hipStream_t stream) {
    const float* x     = (const float*)d_in[0];
    const float* gamma = (const float*)d_in[1];
    const float* beta  = (const float*)d_in[2];
    const float* Wq    = (const float*)d_in[3];
    const float* Wk    = (const float*)d_in[4];
    const float* Wv    = (const float*)d_in[5];
    const float* Wo    = (const float*)d_in[6];
    float* out = (float*)d_out;

    const size_t NELEM = (size_t)MROWS * HH;
    // ws (35.7 MB): Qb bf16 + Vb bf16 + Wslot bf16 (2.1 MB, converted per-GEMM).
    // d_out (33.5 MB f32): Kb bf16 + xn bf16 — dead before final GEMM writes.
    bf16* Qb    = (bf16*)d_ws;
    bf16* Vb    = Qb + NELEM;          // V^T layout [b][h][d][T]
    bf16* Wslot = Vb + NELEM;
    bf16* Kb    = (bf16*)d_out;
    bf16* xnb   = (bf16*)d_out + NELEM;

    ln_k<<<MROWS, 256, 0, stream>>>(x, gamma, beta, xnb);
    dim3 gg(MROWS / 128, HH / 128);
    convw_k<<<HH * HH / 1024, 256, 0, stream>>>(Wq, Wslot);
    gemm_bf128_k<<<gg, 256, 0, stream>>>(xnb, Wslot, Qb, 0);
    convw_k<<<HH * HH / 1024, 256, 0, stream>>>(Wk, Wslot);
    gemm_bf128_k<<<gg, 256, 0, stream>>>(xnb, Wslot, Kb, 0);
    convw_k<<<HH * HH / 1024, 256, 0, stream>>>(Wv, Wslot);
    gemm_bf128_k<<<gg, 256, 0, stream>>>(xnb, Wslot, Vb, 1);
    attn_k<<<TT / 64 * NHEADS * BB, 256, 0, stream>>>(Qb, Kb, Vb, Qb);
    convw_k<<<HH * HH / 1024, 256, 0, stream>>>(Wo, Wslot);
    gemm_finbf_k<<<gg, 256, 0, stream>>>(Qb, Wslot, x, out);
}